// Round 1
// baseline (30137.610 us; speedup 1.0000x reference)
//
#include <hip/hip_runtime.h>
#include <math.h>

#define BATCH 256
#define TT    784
#define HH    512
#define NCLS  10

#define NB 32          // batch groups
#define NJ 8           // j groups
#define MB 8           // rows per batch group   (BATCH/NB)
#define HJ 64          // cols per j group       (HH/NJ)
#define NT 512         // threads per block (8 waves)

// d_ws layout:
//   [0, 4096)                 : barrier counters, NB counters at stride 32 ints (128 B)
//   [4096, 4096 + 2*B*H*4)    : double-buffered h state

__global__ __launch_bounds__(256) void rnn_init_kernel(float* hbuf0, int* cnt) {
    int i = blockIdx.x * blockDim.x + threadIdx.x;
    if (i < BATCH * HH) hbuf0[i] = 0.0f;   // h_0 = 0 (buffer 0)
    if (i < NB * 32)    cnt[i]   = 0;      // barrier counters
}

__global__ __launch_bounds__(NT, 2) void rnn_main_kernel(
    const float* __restrict__ inputs, const int* __restrict__ order,
    const float* __restrict__ W_ih, const float* __restrict__ b_ih,
    const float* __restrict__ W_hh, const float* __restrict__ b_hh,
    float* __restrict__ hbuf, int* cnt)
{
    // 16.7 KB static LDS: h-tile / partials union + small constants
    __shared__ float hp[MB * HH];     // [8][512] h tile, then reused as partials [8kg][8b*64+j]
    __shared__ float wih_s[HJ];
    __shared__ float bias_s[HJ];
    __shared__ float xs[MB];

    const int tid   = threadIdx.x;
    const int blk   = blockIdx.x;
    const int bb    = blk & (NB - 1);   // batch group: stride-32 blocks share bb -> same XCD under %8 round-robin
    const int jj    = blk >> 5;         // j group 0..7
    const int jbase = jj * HJ;
    const int bbase = bb * MB;
    const int j  = tid & 63;            // lane = output column within slice
    const int kg = tid >> 6;            // wave = k-chunk 0..7 (64 k's each)

    // ---- W_hh slice resident in registers for the whole scan: W[jbase+j][kg*64 .. +63]
    float wreg[64];
    {
        const float* wrow = W_hh + (size_t)(jbase + j) * HH + kg * 64;
        #pragma unroll
        for (int i = 0; i < 16; ++i) {
            float4 w4 = *(const float4*)(wrow + i * 4);
            wreg[4*i+0] = w4.x; wreg[4*i+1] = w4.y;
            wreg[4*i+2] = w4.z; wreg[4*i+3] = w4.w;
        }
    }
    if (tid < HJ) {
        wih_s[tid]  = W_ih[jbase + tid];
        bias_s[tid] = b_ih[jbase + tid] + b_hh[jbase + tid];
    }

    int* mycnt = cnt + bb * 32;

    for (int t = 0; t < TT; ++t) {
        const int p = t & 1;
        // ---- group barrier: wait until all NJ blocks of this batch group published h_t
        if (t > 0 && tid == 0) {
            while (__hip_atomic_load(mycnt, __ATOMIC_ACQUIRE, __HIP_MEMORY_SCOPE_AGENT) < NJ * t) { }
        }
        __syncthreads();

        // ---- load h tile (MB x HH = 16 KB) from hbuf[p]
        {
            const float4* src = (const float4*)(hbuf + (size_t)p * BATCH * HH + (size_t)bbase * HH);
            float4* dst = (float4*)hp;
            #pragma unroll
            for (int i = 0; i < (MB * HH / 4) / NT; ++i)   // 2 iters
                dst[tid + i * NT] = src[tid + i * NT];
        }
        if (tid < MB) {
            const int ot = order[t];
            xs[tid] = inputs[(size_t)(bbase + tid) * TT + ot];
        }
        __syncthreads();

        // ---- partial dot products: acc[b] = sum over this wave's 64 k's of h[b][k]*W[j][k]
        float acc[MB];
        #pragma unroll
        for (int b = 0; b < MB; ++b) acc[b] = 0.0f;
        const float4* hT = (const float4*)hp;   // [8][128] float4
        #pragma unroll
        for (int i = 0; i < 16; ++i) {
            const int k4 = kg * 16 + i;
            #pragma unroll
            for (int b = 0; b < MB; ++b) {
                float4 hv = hT[b * 128 + k4];           // wave-uniform broadcast read
                acc[b] = fmaf(wreg[4*i+0], hv.x, acc[b]);
                acc[b] = fmaf(wreg[4*i+1], hv.y, acc[b]);
                acc[b] = fmaf(wreg[4*i+2], hv.z, acc[b]);
                acc[b] = fmaf(wreg[4*i+3], hv.w, acc[b]);
            }
        }
        __syncthreads();                         // all h reads done; hp reusable
        #pragma unroll
        for (int b = 0; b < MB; ++b) hp[kg * 512 + b * 64 + j] = acc[b];  // conflict-free
        __syncthreads();

        // ---- reduce 8 k-chunks, add input/bias, tanh, publish h_{t+1}
        {
            const int rb = tid >> 6;
            const int rj = tid & 63;
            float s = xs[rb] * wih_s[rj] + bias_s[rj];
            #pragma unroll
            for (int g = 0; g < 8; ++g) s += hp[g * 512 + rb * 64 + rj];
            const float hn = tanhf(s);
            hbuf[(size_t)(p ^ 1) * BATCH * HH + (size_t)(bbase + rb) * HH + jbase + rj] = hn;
        }
        __threadfence();     // make h_{t+1} slice visible device-wide
        __syncthreads();
        if (tid == 0) {
            __hip_atomic_fetch_add(mycnt, 1, __ATOMIC_RELEASE, __HIP_MEMORY_SCOPE_AGENT);
        }
    }
}

__global__ __launch_bounds__(256) void rnn_tail_kernel(
    const float* __restrict__ hfin,   // final h in hbuf buffer 0 (T even)
    const float* __restrict__ lin_W, const float* __restrict__ lin_b,
    const int* __restrict__ y, float* __restrict__ out)
{
    __shared__ float redf[256];
    __shared__ int   redi[256];
    const int b = threadIdx.x;
    const float* hrow = hfin + (size_t)b * HH;

    float logits[NCLS];
    #pragma unroll
    for (int c = 0; c < NCLS; ++c) {
        float s = lin_b[c];
        const float* wrow = lin_W + (size_t)c * HH;
        for (int k = 0; k < HH; k += 4) {
            float4 hv = *(const float4*)(hrow + k);
            float4 wv = *(const float4*)(wrow + k);
            s += hv.x * wv.x + hv.y * wv.y + hv.z * wv.z + hv.w * wv.w;
        }
        logits[c] = s;
    }
    int am = 0; float m = logits[0];
    #pragma unroll
    for (int c = 1; c < NCLS; ++c) if (logits[c] > m) { m = logits[c]; am = c; } // first-max = jnp.argmax
    float sum = 0.0f;
    #pragma unroll
    for (int c = 0; c < NCLS; ++c) sum += expf(logits[c] - m);
    const float lse = m + logf(sum);
    const int yy = y[b];
    redf[b] = lse - logits[yy];           // -logp[b, y[b]]
    redi[b] = (am == yy) ? 1 : 0;
    __syncthreads();
    for (int s2 = 128; s2 > 0; s2 >>= 1) {
        if (b < s2) { redf[b] += redf[b + s2]; redi[b] += redi[b + s2]; }
        __syncthreads();
    }
    if (b == 0) {
        out[0] = redf[0] / (float)BATCH;  // loss
        out[1] = (float)redi[0];          // correct count
    }
}

extern "C" void kernel_launch(void* const* d_in, const int* in_sizes, int n_in,
                              void* d_out, int out_size, void* d_ws, size_t ws_size,
                              hipStream_t stream) {
    const float* inputs = (const float*)d_in[0];
    const int*   y      = (const int*)  d_in[1];
    const int*   order  = (const int*)  d_in[2];
    const float* W_ih   = (const float*)d_in[3];
    const float* b_ih   = (const float*)d_in[4];
    const float* W_hh   = (const float*)d_in[5];
    const float* b_hh   = (const float*)d_in[6];
    const float* lin_W  = (const float*)d_in[7];
    const float* lin_b  = (const float*)d_in[8];
    float* out = (float*)d_out;

    int*   cnt  = (int*)d_ws;
    float* hbuf = (float*)((char*)d_ws + 4096);

    hipLaunchKernelGGL(rnn_init_kernel, dim3((BATCH * HH + 255) / 256), dim3(256), 0, stream,
                       hbuf, cnt);

    void* args[] = {(void*)&inputs, (void*)&order, (void*)&W_ih, (void*)&b_ih,
                    (void*)&W_hh, (void*)&b_hh, (void*)&hbuf, (void*)&cnt};
    hipError_t err = hipLaunchCooperativeKernel((void*)rnn_main_kernel,
                                                dim3(NB * NJ), dim3(NT), args, 0, stream);
    if (err != hipSuccess) {
        // fallback: 256 blocks x 1/CU are co-resident on an otherwise-empty device
        hipLaunchKernelGGL(rnn_main_kernel, dim3(NB * NJ), dim3(NT), 0, stream,
                           inputs, order, W_ih, b_ih, W_hh, b_hh, hbuf, cnt);
    }

    hipLaunchKernelGGL(rnn_tail_kernel, dim3(1), dim3(256), 0, stream,
                       (const float*)hbuf, lin_W, lin_b, y, out);
}

// Round 2
// 7111.433 us; speedup vs baseline: 4.2379x; 4.2379x over previous
//
#include <hip/hip_runtime.h>
#include <math.h>

#define BATCH 256
#define TT    784
#define HH    512
#define NCLS  10

#define NB 32          // batch groups
#define NJ 8           // j groups (blocks per group)
#define MB 8           // batch rows per group   (BATCH/NB)
#define HJ 64          // output cols per block  (HH/NJ)
#define NT 512         // threads per block (8 waves)

// d_ws layout:
//   [0, 4096)                 : barrier counters, NB counters at stride 32 ints
//   [4096, 4096 + 2*B*H*4)    : double-buffered h state

__global__ __launch_bounds__(256) void rnn_init_kernel(float* hbuf0, int* cnt) {
    int i = blockIdx.x * blockDim.x + threadIdx.x;
    if (i < BATCH * HH) hbuf0[i] = 0.0f;   // h_0 = 0 (buffer 0)
    if (i < NB * 32)    cnt[i]   = 0;      // barrier counters
}

__global__ __launch_bounds__(NT, 2) void rnn_main_kernel(
    const float* __restrict__ inputs, const int* __restrict__ order,
    const float* __restrict__ W_ih, const float* __restrict__ b_ih,
    const float* __restrict__ W_hh, const float* __restrict__ b_hh,
    float* __restrict__ hbuf, int* cnt)
{
    __shared__ float hp[MB * HH];       // 16 KB: h tile, then reused as partials
    __shared__ float xall[TT * MB];     // 25 KB: pre-gathered inputs[b][order[t]]
    __shared__ float wih_s[HJ];
    __shared__ float bias_s[HJ];

    const int tid   = threadIdx.x;
    const int blk   = blockIdx.x;
    const int bb    = blk & (NB - 1);   // batch group; group members are blk=bb+32g -> same XCD under %8
    const int jj    = blk >> 5;         // j group 0..7
    const int jbase = jj * HJ;
    const int bbase = bb * MB;
    const int j  = tid & 63;            // lane = output column within slice
    const int kg = tid >> 6;            // wave = k-chunk 0..7 (64 k's each)

    // ---- W_hh slice in NAMED registers (no array -> no SROA failure -> no scratch):
    // lane (j,kg) holds W_hh[jbase+j][kg*64 .. kg*64+63] as 16 float4
    const float4* wsrc = (const float4*)(W_hh + (size_t)(jbase + j) * HH + (size_t)kg * 64);
    const float4 w0  = wsrc[0],  w1  = wsrc[1],  w2  = wsrc[2],  w3  = wsrc[3];
    const float4 w4  = wsrc[4],  w5  = wsrc[5],  w6  = wsrc[6],  w7  = wsrc[7];
    const float4 w8  = wsrc[8],  w9  = wsrc[9],  w10 = wsrc[10], w11 = wsrc[11];
    const float4 w12 = wsrc[12], w13 = wsrc[13], w14 = wsrc[14], w15 = wsrc[15];

    if (tid < HJ) {
        wih_s[tid]  = W_ih[jbase + tid];
        bias_s[tid] = b_ih[jbase + tid] + b_hh[jbase + tid];
    }
    // ---- pre-gather all x_t for this batch group: xall[t*MB + b] = inputs[b][order[t]]
    for (int idx = tid; idx < TT * MB; idx += NT) {
        const int t = idx >> 3;          // MB == 8
        const int b = idx & (MB - 1);
        xall[idx] = inputs[(size_t)(bbase + b) * TT + order[t]];
    }

    int* mycnt = cnt + bb * 32;

    for (int t = 0; t < TT; ++t) {
        const int p = t & 1;
        // ---- group barrier: all NJ blocks of this batch group have published h_t
        if (t > 0 && tid == 0) {
            while (__hip_atomic_load(mycnt, __ATOMIC_ACQUIRE, __HIP_MEMORY_SCOPE_AGENT) < NJ * t) { }
        }
        __syncthreads();

        // ---- load h tile (MB x HH = 16 KB) from hbuf[p]
        {
            const float4* src = (const float4*)(hbuf + (size_t)p * BATCH * HH + (size_t)bbase * HH);
            float4* dst = (float4*)hp;
            dst[tid]      = src[tid];
            dst[tid + NT] = src[tid + NT];
        }
        __syncthreads();

        // ---- partial dot products, fully expanded; hB reads are wave-uniform broadcasts
        float a0 = 0.f, a1 = 0.f, a2 = 0.f, a3 = 0.f, a4 = 0.f, a5 = 0.f, a6 = 0.f, a7 = 0.f;
        const float4* hB = ((const float4*)hp) + kg * 16;   // hB[b*128 + i]

#define FMA4(ACC, WV, HV) \
        ACC = fmaf(WV.x, HV.x, ACC); ACC = fmaf(WV.y, HV.y, ACC); \
        ACC = fmaf(WV.z, HV.z, ACC); ACC = fmaf(WV.w, HV.w, ACC);
#define CHUNK(I, WV) { float4 hv; \
        hv = hB[0*128+(I)]; FMA4(a0, WV, hv) \
        hv = hB[1*128+(I)]; FMA4(a1, WV, hv) \
        hv = hB[2*128+(I)]; FMA4(a2, WV, hv) \
        hv = hB[3*128+(I)]; FMA4(a3, WV, hv) \
        hv = hB[4*128+(I)]; FMA4(a4, WV, hv) \
        hv = hB[5*128+(I)]; FMA4(a5, WV, hv) \
        hv = hB[6*128+(I)]; FMA4(a6, WV, hv) \
        hv = hB[7*128+(I)]; FMA4(a7, WV, hv) }

        CHUNK(0,  w0)  CHUNK(1,  w1)  CHUNK(2,  w2)  CHUNK(3,  w3)
        CHUNK(4,  w4)  CHUNK(5,  w5)  CHUNK(6,  w6)  CHUNK(7,  w7)
        CHUNK(8,  w8)  CHUNK(9,  w9)  CHUNK(10, w10) CHUNK(11, w11)
        CHUNK(12, w12) CHUNK(13, w13) CHUNK(14, w14) CHUNK(15, w15)
#undef CHUNK
#undef FMA4

        __syncthreads();                 // all h reads done; hp reusable as partials
        hp[kg * 512 + 0 * 64 + j] = a0;
        hp[kg * 512 + 1 * 64 + j] = a1;
        hp[kg * 512 + 2 * 64 + j] = a2;
        hp[kg * 512 + 3 * 64 + j] = a3;
        hp[kg * 512 + 4 * 64 + j] = a4;
        hp[kg * 512 + 5 * 64 + j] = a5;
        hp[kg * 512 + 6 * 64 + j] = a6;
        hp[kg * 512 + 7 * 64 + j] = a7;
        __syncthreads();

        // ---- reduce 8 k-chunks, add input/bias, tanh, publish h_{t+1}
        {
            const int rb = tid >> 6;
            const int rj = tid & 63;
            float s = xall[t * MB + rb] * wih_s[rj] + bias_s[rj];
            s += hp[0 * 512 + rb * 64 + rj];
            s += hp[1 * 512 + rb * 64 + rj];
            s += hp[2 * 512 + rb * 64 + rj];
            s += hp[3 * 512 + rb * 64 + rj];
            s += hp[4 * 512 + rb * 64 + rj];
            s += hp[5 * 512 + rb * 64 + rj];
            s += hp[6 * 512 + rb * 64 + rj];
            s += hp[7 * 512 + rb * 64 + rj];
            const float hn = tanhf(s);
            hbuf[(size_t)(p ^ 1) * BATCH * HH + (size_t)(bbase + rb) * HH + jbase + rj] = hn;
        }
        __syncthreads();
        if (tid == 0) {
            // RELEASE orders the h stores above before the counter becomes visible
            __hip_atomic_fetch_add(mycnt, 1, __ATOMIC_RELEASE, __HIP_MEMORY_SCOPE_AGENT);
        }
    }
}

__global__ __launch_bounds__(256) void rnn_tail_kernel(
    const float* __restrict__ hfin,   // final h in hbuf buffer 0 (T even)
    const float* __restrict__ lin_W, const float* __restrict__ lin_b,
    const int* __restrict__ y, float* __restrict__ out)
{
    __shared__ float redf[256];
    __shared__ int   redi[256];
    const int b = threadIdx.x;
    const float* hrow = hfin + (size_t)b * HH;

    float logits[NCLS];
    #pragma unroll
    for (int c = 0; c < NCLS; ++c) {
        float s = lin_b[c];
        const float* wrow = lin_W + (size_t)c * HH;
        for (int k = 0; k < HH; k += 4) {
            float4 hv = *(const float4*)(hrow + k);
            float4 wv = *(const float4*)(wrow + k);
            s += hv.x * wv.x + hv.y * wv.y + hv.z * wv.z + hv.w * wv.w;
        }
        logits[c] = s;
    }
    int am = 0; float m = logits[0];
    #pragma unroll
    for (int c = 1; c < NCLS; ++c) if (logits[c] > m) { m = logits[c]; am = c; } // first-max = jnp.argmax
    float sum = 0.0f;
    #pragma unroll
    for (int c = 0; c < NCLS; ++c) sum += expf(logits[c] - m);
    const float lse = m + logf(sum);
    const int yy = y[b];
    redf[b] = lse - logits[yy];           // -logp[b, y[b]]
    redi[b] = (am == yy) ? 1 : 0;
    __syncthreads();
    for (int s2 = 128; s2 > 0; s2 >>= 1) {
        if (b < s2) { redf[b] += redf[b + s2]; redi[b] += redi[b + s2]; }
        __syncthreads();
    }
    if (b == 0) {
        out[0] = redf[0] / (float)BATCH;  // loss
        out[1] = (float)redi[0];          // correct count
    }
}

extern "C" void kernel_launch(void* const* d_in, const int* in_sizes, int n_in,
                              void* d_out, int out_size, void* d_ws, size_t ws_size,
                              hipStream_t stream) {
    const float* inputs = (const float*)d_in[0];
    const int*   y      = (const int*)  d_in[1];
    const int*   order  = (const int*)  d_in[2];
    const float* W_ih   = (const float*)d_in[3];
    const float* b_ih   = (const float*)d_in[4];
    const float* W_hh   = (const float*)d_in[5];
    const float* b_hh   = (const float*)d_in[6];
    const float* lin_W  = (const float*)d_in[7];
    const float* lin_b  = (const float*)d_in[8];
    float* out = (float*)d_out;

    int*   cnt  = (int*)d_ws;
    float* hbuf = (float*)((char*)d_ws + 4096);

    hipLaunchKernelGGL(rnn_init_kernel, dim3((BATCH * HH + 255) / 256), dim3(256), 0, stream,
                       hbuf, cnt);

    void* args[] = {(void*)&inputs, (void*)&order, (void*)&W_ih, (void*)&b_ih,
                    (void*)&W_hh, (void*)&b_hh, (void*)&hbuf, (void*)&cnt};
    hipError_t err = hipLaunchCooperativeKernel((void*)rnn_main_kernel,
                                                dim3(NB * NJ), dim3(NT), args, 0, stream);
    if (err != hipSuccess) {
        // fallback: 256 blocks x 1/CU are co-resident on an otherwise-empty device
        hipLaunchKernelGGL(rnn_main_kernel, dim3(NB * NJ), dim3(NT), 0, stream,
                           inputs, order, W_ih, b_ih, W_hh, b_hh, hbuf, cnt);
    }

    hipLaunchKernelGGL(rnn_tail_kernel, dim3(1), dim3(256), 0, stream,
                       (const float*)hbuf, lin_W, lin_b, y, out);
}